// Round 7
// baseline (172.539 us; speedup 1.0000x reference)
//
#include <hip/hip_runtime.h>

#define G_ 100
#define T_ 24
#define GP1 101
#define TILE (G_ * T_)        // 2400 floats per (b,pass) tile
#define VPB (TILE / 4)        // 600 float4 per tile
#define BLOCK 256             // 4 independent waves; wave owns one b
#define WPB 4

typedef float vfloat4 __attribute__((ext_vector_type(4)));

// One block, once: prices + stable rank-sort (== jnp.argsort) into workspace.
__global__ void setup_sort_kernel(const float* __restrict__ b_G,
                                  const float* __restrict__ voll,
                                  const float* __restrict__ vosp,
                                  const float* __restrict__ ru,
                                  const float* __restrict__ rd,
                                  int* __restrict__ order_out,     // [2][101]
                                  float* __restrict__ price_out)   // [2][101]
{
    __shared__ float pu[GP1], pd[GP1];
    int i = threadIdx.x;
    if (i < GP1) {
        if (i < G_) { float bg = b_G[i]; pu[i] = ru[0] * bg; pd[i] = rd[0] * bg; }
        else        { pu[i] = voll[0];   pd[i] = vosp[0]; }
    }
    __syncthreads();
    if (i < GP1) {
        float mu = pu[i], md = pd[i];
        int r0 = 0, r1 = 0;
        for (int j = 0; j < GP1; ++j) {
            float vu = pu[j], vd = pd[j];
            r0 += (vu < mu) || (vu == mu && j < i);
            r1 += (vd < md) || (vd == md && j < i);
        }
        order_out[r0] = i;        price_out[r0] = mu;
        order_out[GP1 + r1] = i;  price_out[GP1 + r1] = md;
    }
}

// Batched in-LDS merit-order chunk; ord/price are wave-uniform scalar loads.
// In-place cap -> alloc (each g touched exactly once at k = rank[g]).
template<int N>
__device__ __forceinline__ void scan_chunk(int k0,
    float* __restrict__ tile, const int* __restrict__ ordp,
    const float* __restrict__ prp, float dem,
    float& before, float& objp, float& slackv)
{
    int gg[N]; float pr[N], cap[N];
#pragma unroll
    for (int j = 0; j < N; ++j) { gg[j] = ordp[k0 + j]; pr[j] = prp[k0 + j]; }
#pragma unroll
    for (int j = 0; j < N; ++j) {
        int gl = (gg[j] < G_) ? gg[j] : 0;          // slack slot: dummy read
        cap[j] = tile[gl * T_];
    }
#pragma unroll
    for (int j = 0; j < N; ++j) {
        float c = (gg[j] == G_) ? dem : cap[j];
        float a = fminf(fmaxf(dem - before, 0.f), c);
        before += c;
        objp = fmaf(pr[j], a, objp);
        if (gg[j] == G_) slackv = a;
        else             tile[gg[j] * T_] = a;      // own column only
    }
}

__global__ __launch_bounds__(BLOCK, 4) void dispatch_kernel(
    const float* __restrict__ R_up, const float* __restrict__ R_dn,
    const float* __restrict__ omega,
    const int* __restrict__ ord_ws, const float* __restrict__ pr_ws,
    float* __restrict__ out, int B)
{
    __shared__ float s_tile[WPB * TILE];            // 38400 B -> 4 blocks/CU

    const int tid  = threadIdx.x;
    const int w    = tid >> 6;
    const int lane = tid & 63;
    const int b    = __builtin_amdgcn_readfirstlane(blockIdx.x * WPB + w);
    const size_t bgt = (size_t)B * TILE;
    float* __restrict__ tw = &s_tile[w * TILE];     // wave-private slice

    // ---- prefetch pass-0 tile (contiguous 9600 B, 10 float4/lane-round) ----
    vfloat4 buf[10];
    {
        const vfloat4* __restrict__ s0 = (const vfloat4*)R_up + (size_t)b * VPB;
#pragma unroll
        for (int j = 0; j < 9; ++j) buf[j] = s0[lane + j * 64];
        if (lane < VPB - 576) buf[9] = s0[lane + 576];
    }
    float om = 0.f;
    if (lane < T_) om = omega[(size_t)b * T_ + lane];

    float objsum = 0.f;
#pragma unroll
    for (int p = 0; p < 2; ++p) {
        // ---- stage regs -> LDS (compiler waits vmcnt on buf only) ----
#pragma unroll
        for (int j = 0; j < 9; ++j) *(vfloat4*)&tw[(lane + j * 64) * 4] = buf[j];
        if (lane < VPB - 576)       *(vfloat4*)&tw[(lane + 576) * 4]    = buf[9];
        __builtin_amdgcn_wave_barrier();

        // ---- issue pass-1 prefetch; latency hides under the scan ----
        if (p == 0) {
            const vfloat4* __restrict__ s1 = (const vfloat4*)R_dn + (size_t)b * VPB;
#pragma unroll
            for (int j = 0; j < 9; ++j) buf[j] = s1[lane + j * 64];
            if (lane < VPB - 576) buf[9] = s1[lane + 576];
        }

        // ---- merit-order scan in LDS (24 lanes) ----
        float objp = 0.f;
        if (lane < T_) {
            const float dem = p ? fmaxf(-om, 0.f) : fmaxf(om, 0.f);
            float* __restrict__ tile = tw + lane;
            const int*   __restrict__ ordp = ord_ws + p * GP1;
            const float* __restrict__ prp  = pr_ws  + p * GP1;
            float before = 0.f, slackv = 0.f;
            scan_chunk<16>( 0, tile, ordp, prp, dem, before, objp, slackv);
            scan_chunk<16>(16, tile, ordp, prp, dem, before, objp, slackv);
            scan_chunk<16>(32, tile, ordp, prp, dem, before, objp, slackv);
            scan_chunk<16>(48, tile, ordp, prp, dem, before, objp, slackv);
            scan_chunk<16>(64, tile, ordp, prp, dem, before, objp, slackv);
            scan_chunk<16>(80, tile, ordp, prp, dem, before, objp, slackv);
            scan_chunk< 5>(96, tile, ordp, prp, dem, before, objp, slackv);
            out[2 * bgt + (size_t)p * B * T_ + (size_t)b * T_ + lane] = slackv;
        }
        __builtin_amdgcn_wave_barrier();

        // ---- rt_obj partial: butterfly over the wave (lanes >=24 hold 0) ----
#pragma unroll
        for (int off = 32; off; off >>= 1) objp += __shfl_xor(objp, off, 64);
        objsum += objp;

        // ---- store LDS -> global, coalesced plain float4 ----
        {
            vfloat4* __restrict__ dst = (vfloat4*)out + ((size_t)p * B + b) * VPB;
#pragma unroll
            for (int j = 0; j < 9; ++j)
                dst[lane + j * 64] = *(const vfloat4*)&tw[(lane + j * 64) * 4];
            if (lane < VPB - 576)
                dst[lane + 576] = *(const vfloat4*)&tw[(lane + 576) * 4];
        }
        __builtin_amdgcn_wave_barrier();
    }

    if (lane == 0)
        out[2 * bgt + 2 * (size_t)B * T_ + b] = objsum;
}

extern "C" void kernel_launch(void* const* d_in, const int* in_sizes, int n_in,
                              void* d_out, int out_size, void* d_ws, size_t ws_size,
                              hipStream_t stream)
{
    const float* R_up  = (const float*)d_in[0];
    const float* R_dn  = (const float*)d_in[1];
    const float* omega = (const float*)d_in[2];
    const float* b_G   = (const float*)d_in[3];
    const float* voll  = (const float*)d_in[4];
    const float* vosp  = (const float*)d_in[5];
    const float* ru    = (const float*)d_in[6];
    const float* rd    = (const float*)d_in[7];

    const int B = in_sizes[0] / TILE;
    float* out = (float*)d_out;

    int*   ord_ws = (int*)d_ws;
    float* pr_ws  = (float*)((char*)d_ws + 2 * GP1 * sizeof(int));

    setup_sort_kernel<<<1, 128, 0, stream>>>(b_G, voll, vosp, ru, rd, ord_ws, pr_ws);

    // one wave per b: B waves -> B/4 blocks (B=4096 -> 1024, one full generation)
    dispatch_kernel<<<B / WPB, BLOCK, 0, stream>>>(
        R_up, R_dn, omega, ord_ws, pr_ws, out, B);
}